// Round 10
// baseline (792.330 us; speedup 1.0000x reference)
//
#include <hip/hip_runtime.h>

#define NN 50000
#define NE 800000
#define IND 128
#define NH 8
#define DH 16
#define NR 9
#define KTOT 1152     // NR*IND
#define NOUT 384      // 3*IND
#define OB_N 24       // NOUT/16
#define NBLK 196      // ceil(NN/256)

typedef __attribute__((ext_vector_type(8))) short bf16x8;
typedef __attribute__((ext_vector_type(4))) float f32x4;

__device__ __forceinline__ ushort f2bf(float x) {
  unsigned u = __float_as_uint(x);
  u += 0x7FFF + ((u >> 16) & 1);          // RNE
  return (ushort)(u >> 16);
}
__device__ __forceinline__ float bf2f(ushort h) {
  return __uint_as_float(((unsigned)h) << 16);
}

// ---- W precompute: frag-linear hi/lo bf16 for W[k = r*128+i][o = m*128+oc] -
// frag-linear: [kb][ob][lane][j], lane = ((k%32)/8)*16 + (o%16), j = k%8
__global__ __launch_bounds__(256) void make_w(const float* __restrict__ Qw, const float* __restrict__ Qc,
                                              const float* __restrict__ Kw, const float* __restrict__ Kc,
                                              const float* __restrict__ Vw, const float* __restrict__ Vc,
                                              ushort* __restrict__ Wh, ushort* __restrict__ Wl) {
  int t = blockIdx.x * 256 + threadIdx.x;     // 0..442367 (exact grid)
  int k = t / NOUT;
  int og = t % NOUT;
  int r = k >> 7, i = k & 127;
  int m = og >> 7, oc = og & 127;
  const float* basis = m == 0 ? Qw : m == 1 ? Kw : Vw;
  const float* comb  = m == 0 ? Qc : m == 1 ? Kc : Vc;
  float w = 0.f;
#pragma unroll
  for (int b = 0; b < NR; ++b)
    w += comb[r * NR + b] * basis[(long)b * IND * IND + i * IND + oc];
  ushort hi = f2bf(w);
  ushort lo = f2bf(w - bf2f(hi));
  long idx = ((long)(k >> 5) * OB_N + (og >> 4)) * 512
           + (((k >> 3) & 3) * 16 + (og & 15)) * 8 + (k & 7);
  Wh[idx] = hi;
  Wl[idx] = lo;
}

// ---------------- CSR build (proven in round 2) -----------------------------
__global__ __launch_bounds__(256) void hist_dst(const int* __restrict__ dst,
                                                int* __restrict__ deg) {
  int e = blockIdx.x * 256 + threadIdx.x;
  if (e < NE) atomicAdd(&deg[dst[e]], 1);
}

__global__ __launch_bounds__(256) void scan_p1(const int* __restrict__ deg,
                                               int* __restrict__ bsum) {
  __shared__ int sb[256];
  int t = threadIdx.x;
  int idx = blockIdx.x * 256 + t;
  int v = (idx < NN) ? deg[idx] : 0;
  sb[t] = v;
  __syncthreads();
  for (int off = 128; off > 0; off >>= 1) {
    if (t < off) sb[t] += sb[t + off];
    __syncthreads();
  }
  if (t == 0) bsum[blockIdx.x] = sb[0];
}

__global__ __launch_bounds__(256) void scan_p2(const int* __restrict__ bsum,
                                               int* __restrict__ boff,
                                               int* __restrict__ rowptr) {
  __shared__ int sb[256];
  int t = threadIdx.x;
  int v = (t < NBLK) ? bsum[t] : 0;
  sb[t] = v;
  __syncthreads();
  for (int off = 1; off < 256; off <<= 1) {
    int add = (t >= off) ? sb[t - off] : 0;
    __syncthreads();
    sb[t] += add;
    __syncthreads();
  }
  if (t < NBLK) boff[t] = sb[t] - v;   // exclusive
  if (t == 0) rowptr[NN] = NE;
}

__global__ __launch_bounds__(256) void scan_p3(const int* __restrict__ deg,
                                               const int* __restrict__ boff,
                                               int* __restrict__ rowptr,
                                               int* __restrict__ cursor) {
  __shared__ int sb[256];
  int t = threadIdx.x;
  int idx = blockIdx.x * 256 + t;
  int v = (idx < NN) ? deg[idx] : 0;
  sb[t] = v;
  __syncthreads();
  for (int off = 1; off < 256; off <<= 1) {
    int add = (t >= off) ? sb[t - off] : 0;
    __syncthreads();
    sb[t] += add;
    __syncthreads();
  }
  if (idx < NN) {
    int excl = sb[t] - v + boff[blockIdx.x];
    rowptr[idx] = excl;
    cursor[idx] = excl;
  }
}

__global__ __launch_bounds__(256) void bucket_edges(const int* __restrict__ src,
                                                    const int* __restrict__ dst,
                                                    const int* __restrict__ et,
                                                    int* __restrict__ cursor,
                                                    int* __restrict__ epk) {
  int e = blockIdx.x * 256 + threadIdx.x;
  if (e >= NE) return;
  int d = dst[e];
  int pos = atomicAdd(&cursor[d], 1);
  epk[pos] = src[e] | (et[e] << 20);   // src < 2^17, et < 16
}

// ---- per-node relational aggregation -> chunked hi/lo bf16 A ---------------
// A layout: [rr - rlo][n][128]; 4 edges in flight per iteration (MLP).
__global__ __launch_bounds__(256) void conv_agg(const float* __restrict__ x,
                                                const int* __restrict__ rowptr,
                                                const int* __restrict__ epk,
                                                ushort* __restrict__ Ah,
                                                ushort* __restrict__ Al,
                                                int rlo, int rhi) {
  int wid = (blockIdx.x * 256 + threadIdx.x) >> 6;
  int lane = threadIdx.x & 63;
  if (wid >= NN) return;
  float ax[NR], ay[NR];
#pragma unroll
  for (int rr = 0; rr < NR; ++rr) { ax[rr] = 0.f; ay[rr] = 0.f; }

  auto ACC = [&](int p, float2 xv) {
    int r = p >> 20;
#pragma unroll
    for (int rr = 0; rr < NR; ++rr)
      if (r == rr) { ax[rr] += xv.x; ay[rr] += xv.y; }
  };

  int r0 = rowptr[wid], r1 = rowptr[wid + 1];
  for (int base = r0; base < r1; base += 64) {
    int pe = (base + lane < r1) ? epk[base + lane] : 0;
    int cnt = min(64, r1 - base);
    int j = 0;
    for (; j + 4 <= cnt; j += 4) {
      int p0 = __shfl(pe, j);
      int p1 = __shfl(pe, j + 1);
      int p2 = __shfl(pe, j + 2);
      int p3 = __shfl(pe, j + 3);
      float2 x0 = *(const float2*)(x + (long)(p0 & 0xFFFFF) * IND + lane * 2);
      float2 x1 = *(const float2*)(x + (long)(p1 & 0xFFFFF) * IND + lane * 2);
      float2 x2 = *(const float2*)(x + (long)(p2 & 0xFFFFF) * IND + lane * 2);
      float2 x3 = *(const float2*)(x + (long)(p3 & 0xFFFFF) * IND + lane * 2);
      ACC(p0, x0); ACC(p1, x1); ACC(p2, x2); ACC(p3, x3);
    }
    for (; j < cnt; ++j) {
      int p = __shfl(pe, j);
      float2 xv = *(const float2*)(x + (long)(p & 0xFFFFF) * IND + lane * 2);
      ACC(p, xv);
    }
  }
#pragma unroll
  for (int rr = 0; rr < NR; ++rr)
    if (rr >= rlo && rr < rhi) {
      ushort h0 = f2bf(ax[rr]);
      ushort l0 = f2bf(ax[rr] - bf2f(h0));
      ushort h1 = f2bf(ay[rr]);
      ushort l1 = f2bf(ay[rr] - bf2f(h1));
      long o = ((long)(rr - rlo) * NN + wid) * IND + lane * 2;
      *(unsigned*)(Ah + o) = (unsigned)h0 | ((unsigned)h1 << 16);
      *(unsigned*)(Al + o) = (unsigned)l0 | ((unsigned)l1 << 16);
    }
}

// ---- MFMA GEMM v3: 256 thr = 4 waves (wc 0..3); wave tile 64 x 96 ----------
// Block 64 x 384, grid 782 (~3 blocks/CU: even balance + wave-overlap latency
// hiding per m114). A prefetch ping-pong; W single-buffered (L2-resident).
// 3-term bf16 split. No LDS, no barriers.
__global__ __launch_bounds__(256) void gemm_mfma(const ushort* __restrict__ Ah,
                                                 const ushort* __restrict__ Al,
                                                 const ushort* __restrict__ Wh,
                                                 const ushort* __restrict__ Wl,
                                                 const float* __restrict__ Qb,
                                                 const float* __restrict__ Kb,
                                                 const float* __restrict__ Vb,
                                                 float* __restrict__ F,
                                                 int nrel, int rlo, int first, int last) {
  const int tid = threadIdx.x;
  const int lane = tid & 63;
  const int wc = tid >> 6;            // 0..3
  const int n0 = blockIdx.x * 64;
  const int l15 = lane & 15;
  const int kg = lane >> 4;           // 0..3
  const int kgofs = kg * 8;

  long rowOff[4];
#pragma unroll
  for (int mi = 0; mi < 4; ++mi)
    rowOff[mi] = (long)min(n0 + mi * 16 + l15, NN - 1) * IND;

  const int nsteps = nrel * 4;        // multiple of 4, loop unrolled by 2

  f32x4 acc[4][6];
#pragma unroll
  for (int mi = 0; mi < 4; ++mi)
#pragma unroll
    for (int ni = 0; ni < 6; ++ni) acc[mi][ni] = (f32x4){0.f, 0.f, 0.f, 0.f};

  bf16x8 a0[8], a1[8], w[12];

  auto LOADA = [&](bf16x8* A, int s) {
    const long ab = ((long)(s >> 2) * NN) * IND + ((s & 3) * 32 + kgofs);
#pragma unroll
    for (int mi = 0; mi < 4; ++mi) {
      A[mi]     = *(const bf16x8*)(Ah + ab + rowOff[mi]);
      A[4 + mi] = *(const bf16x8*)(Al + ab + rowOff[mi]);
    }
  };
  auto LOADW = [&](bf16x8* W, int s) {
    const long wb = (((long)(rlo * 4 + s) * OB_N + wc * 6) * 64 + lane) * 8;
#pragma unroll
    for (int ni = 0; ni < 6; ++ni) {
      W[ni]     = *(const bf16x8*)(Wh + wb + ni * 512);
      W[6 + ni] = *(const bf16x8*)(Wl + wb + ni * 512);
    }
  };
  auto DOMFMA = [&](bf16x8* A, bf16x8* W) {
#pragma unroll
    for (int ni = 0; ni < 6; ++ni)
#pragma unroll
      for (int mi = 0; mi < 4; ++mi) {
        acc[mi][ni] = __builtin_amdgcn_mfma_f32_16x16x32_bf16(A[mi],     W[6 + ni], acc[mi][ni], 0, 0, 0);
        acc[mi][ni] = __builtin_amdgcn_mfma_f32_16x16x32_bf16(A[4 + mi], W[ni],     acc[mi][ni], 0, 0, 0);
        acc[mi][ni] = __builtin_amdgcn_mfma_f32_16x16x32_bf16(A[mi],     W[ni],     acc[mi][ni], 0, 0, 0);
      }
  };

  LOADA(a0, 0);
  LOADW(w, 0);
  for (int s = 0; s < nsteps; s += 2) {
    LOADA(a1, s + 1);                  // prefetch next A
    DOMFMA(a0, w);                     // step s
    LOADW(w, s + 1);
    if (s + 2 < nsteps) LOADA(a0, s + 2);
    DOMFMA(a1, w);                     // step s+1
    if (s + 2 < nsteps) LOADW(w, s + 2);
  }

#pragma unroll
  for (int mi = 0; mi < 4; ++mi) {
#pragma unroll
    for (int ni = 0; ni < 6; ++ni) {
      int og = wc * 96 + ni * 16 + l15;          // 0..383, C/D col = lane&15
      int m = og >> 7, oc = og & 127;
      float b = (m == 0 ? Qb : m == 1 ? Kb : Vb)[oc];
      float* Fm = F + (long)m * NN * IND;
#pragma unroll
      for (int reg = 0; reg < 4; ++reg) {
        int n = n0 + mi * 16 + kg * 4 + reg;     // C/D row = (lane>>4)*4+reg
        if (n < NN) {
          long fo = (long)n * IND + oc;
          float v = acc[mi][ni][reg];
          if (!first) v += Fm[fo];
          if (last) { v += b; v = v > 0.f ? v : 0.f; }
          Fm[fo] = v;
        }
      }
    }
  }
}

// ---- per-node attention (no atomics, fused normalize; 2-edge MLP) ----------
__global__ __launch_bounds__(256) void node_attn(const float* __restrict__ Q,
                                                 const float* __restrict__ K,
                                                 const float* __restrict__ V,
                                                 const int* __restrict__ rowptr,
                                                 const int* __restrict__ epk,
                                                 float* __restrict__ out) {
  int wid = (blockIdx.x * 256 + threadIdx.x) >> 6;
  int lane = threadIdx.x & 63;
  if (wid >= NN) return;
  float2 q = *(const float2*)(Q + (long)wid * IND + lane * 2);
  float accx = 0.f, accy = 0.f, zacc = 0.f;
  int r0 = rowptr[wid], r1 = rowptr[wid + 1];
  for (int base = r0; base < r1; base += 64) {
    int pe = (base + lane < r1) ? epk[base + lane] : 0;
    int cnt = min(64, r1 - base);
    int j = 0;
    for (; j + 2 <= cnt; j += 2) {
      long s0 = (long)(__shfl(pe, j) & 0xFFFFF) * IND + lane * 2;
      long s1 = (long)(__shfl(pe, j + 1) & 0xFFFFF) * IND + lane * 2;
      float2 k0 = *(const float2*)(K + s0);
      float2 v0 = *(const float2*)(V + s0);
      float2 k1 = *(const float2*)(K + s1);
      float2 v1 = *(const float2*)(V + s1);
      float p0 = q.x * k0.x + q.y * k0.y;
      float p1 = q.x * k1.x + q.y * k1.y;
      p0 += __shfl_xor(p0, 1);
      p1 += __shfl_xor(p1, 1);
      p0 += __shfl_xor(p0, 2);
      p1 += __shfl_xor(p1, 2);
      p0 += __shfl_xor(p0, 4);
      p1 += __shfl_xor(p1, 4);
      float sc0 = __expf(fminf(fmaxf(p0 * 0.25f, -10.f), 10.f));
      float sc1 = __expf(fminf(fmaxf(p1 * 0.25f, -10.f), 10.f));
      accx += sc0 * v0.x + sc1 * v1.x;
      accy += sc0 * v0.y + sc1 * v1.y;
      zacc += sc0 + sc1;
    }
    for (; j < cnt; ++j) {
      long s = (long)(__shfl(pe, j) & 0xFFFFF) * IND + lane * 2;
      float2 k = *(const float2*)(K + s);
      float2 v = *(const float2*)(V + s);
      float p = q.x * k.x + q.y * k.y;
      p += __shfl_xor(p, 1);
      p += __shfl_xor(p, 2);
      p += __shfl_xor(p, 4);
      float score = __expf(fminf(fmaxf(p * 0.25f, -10.f), 10.f));
      accx += score * v.x;
      accy += score * v.y;
      zacc += score;
    }
  }
  float inv = 1.f / (zacc + 1e-6f);
  *(float2*)(out + (long)wid * IND + lane * 2) = make_float2(accx * inv, accy * inv);
}

// ---------------- host ------------------------------------------------------
extern "C" void kernel_launch(void* const* d_in, const int* in_sizes, int n_in,
                              void* d_out, int out_size, void* d_ws, size_t ws_size,
                              hipStream_t stream) {
  const float* h  = (const float*)d_in[0];
  const float* Qw = (const float*)d_in[1];
  const float* Qc = (const float*)d_in[2];
  const float* Qb = (const float*)d_in[3];
  const float* Kw = (const float*)d_in[4];
  const float* Kc = (const float*)d_in[5];
  const float* Kb = (const float*)d_in[6];
  const float* Vw = (const float*)d_in[7];
  const float* Vc = (const float*)d_in[8];
  const float* Vb = (const float*)d_in[9];
  const int* src = (const int*)d_in[10];
  const int* dst = (const int*)d_in[11];
  const int* et  = (const int*)d_in[12];
  float* out = (float*)d_out;

  // ---- workspace layout: all in d_ws, fixed part 82.37 MB; peak C=9 needs
  // 312.77 MB < round-2-proven ws_size >= 316.3 MB.
  char* p = (char*)d_ws;
  ushort* Wh = (ushort*)p;  p += (long)KTOT * NOUT * 2;    // 884,736 B
  ushort* Wl = (ushort*)p;  p += (long)KTOT * NOUT * 2;    // 884,736 B
  float* F   = (float*)p;   p += 3L * NN * IND * 4;        // 76,800,000 B
  int* deg    = (int*)p;
  int* rowptr = deg + NN;
  int* cursor = rowptr + NN + 1;
  int* bsum   = cursor + NN;
  int* boff   = bsum + NBLK;
  int* epk    = boff + NBLK;
  long intbytes = (((long)(3 * NN + 1 + 2 * NBLK + NE)) * 4 + 15) & ~15L;
  p += intbytes;
  ushort* Ah = (ushort*)p;
  long fixed = (long)(p - (char*)d_ws);
  long per_rel = 2L * NN * IND * 2;                         // Ah+Al, 25.6 MB/rel
  int C = (int)(((long)ws_size - fixed) / per_rel);
  if (C > NR) C = NR;
  if (C < 1) C = 1;
  ushort* Al = Ah + (long)C * NN * IND;

  hipMemsetAsync(deg, 0, (size_t)NN * 4, stream);

  make_w<<<(KTOT * NOUT) / 256, 256, 0, stream>>>(Qw, Qc, Kw, Kc, Vw, Vc, Wh, Wl);

  const int eb = (NE + 255) / 256;              // 3125
  hist_dst<<<eb, 256, 0, stream>>>(dst, deg);
  scan_p1<<<NBLK, 256, 0, stream>>>(deg, bsum);
  scan_p2<<<1, 256, 0, stream>>>(bsum, boff, rowptr);
  scan_p3<<<NBLK, 256, 0, stream>>>(deg, boff, rowptr, cursor);
  bucket_edges<<<eb, 256, 0, stream>>>(src, dst, et, cursor, epk);

  const int nwb = (NN * 64 + 255) / 256;        // 12500
  const int gb  = (NN + 63) / 64;               // 782

  int first = 1;
  for (int rlo = 0; rlo < NR; rlo += C) {
    int rhi = rlo + C;
    if (rhi > NR) rhi = NR;
    conv_agg<<<nwb, 256, 0, stream>>>(h, rowptr, epk, Ah, Al, rlo, rhi);
    gemm_mfma<<<gb, 256, 0, stream>>>(Ah, Al, Wh, Wl, Qb, Kb, Vb, F,
                                      rhi - rlo, rlo, first, (rhi == NR) ? 1 : 0);
    first = 0;
  }

  node_attn<<<nwb, 256, 0, stream>>>(F, F + (long)NN * IND, F + 2L * NN * IND,
                                     rowptr, epk, out);
}